// Round 1
// baseline (310.368 us; speedup 1.0000x reference)
//
#include <hip/hip_runtime.h>

#define HWp 4096
#define Wd 64
#define Hd 64
#define CIN_ 128
#define COUT_ 128

// ---------------------------------------------------------------------------
// K1: repack w (o,c,ky,kx) -> w_t[(c*9+k)*128 + o] for coalesced GEMM staging
// ---------------------------------------------------------------------------
__global__ __launch_bounds__(256) void repack_w_kernel(
    const float* __restrict__ w, float* __restrict__ w_t)
{
    int i = blockIdx.x * 256 + threadIdx.x;    // i = o*1152 + ck, total 147456
    int o = i / 1152;
    int ck = i - o * 1152;
    w_t[ck * 128 + o] = w[i];
}

// ---------------------------------------------------------------------------
// K2: offset conv (4 used channels) + bilinear metadata per (b,k,p)
// block = (b, h-row). 256 thr = 64 w-positions x 4 c-chunks of 32.
// ---------------------------------------------------------------------------
__global__ __launch_bounds__(256, 2) void offsets_kernel(
    const float* __restrict__ x, const float* __restrict__ w_off,
    const float* __restrict__ b_off, int4* __restrict__ midx,
    float4* __restrict__ mw)
{
    __shared__ float wl[1152 * 4];   // [(cg*9+tap)*4 + j]  (float4 per tap)
    __shared__ float part[256 * 4];
    __shared__ float der[64 * 4];    // per position: sy, sx, scale1, scale2

    int t = threadIdx.x;
    int b = blockIdx.x >> 6;
    int h = blockIdx.x & 63;

    for (int i = t; i < 4608; i += 256) {
        int j = i / 1152;
        int r = i - j * 1152;        // cg*9 + tap
        wl[r * 4 + j] = w_off[i];
    }
    __syncthreads();

    int pi = t & 63;   // w coordinate
    int cc = t >> 6;   // c-chunk 0..3
    const float* xb = x + (size_t)(b * CIN_ + cc * 32) * HWp;
    float o0 = 0.f, o1 = 0.f, o2 = 0.f, o3 = 0.f;

    for (int c = 0; c < 32; c++) {
        const float* xp = xb + c * HWp;
        const float* wbase = &wl[(cc * 32 + c) * 36];
        #pragma unroll
        for (int dy = -1; dy <= 1; dy++) {
            int hy = h + dy;
            if (hy < 0 || hy >= Hd) continue;      // wave-uniform
            const float* row = xp + hy * Wd;
            #pragma unroll
            for (int dx = -1; dx <= 1; dx++) {
                int wxc = pi + dx;
                float v = (wxc >= 0 && wxc < Wd) ? row[wxc] : 0.0f;
                int tap = (dy + 1) * 3 + (dx + 1);
                float4 wj = *(const float4*)&wbase[tap * 4];
                o0 += v * wj.x; o1 += v * wj.y; o2 += v * wj.z; o3 += v * wj.w;
            }
        }
    }
    part[t * 4 + 0] = o0;
    part[t * 4 + 1] = o1;
    part[t * 4 + 2] = o2;
    part[t * 4 + 3] = o3;
    __syncthreads();

    if (t < 64) {
        float s0 = b_off[0], s1 = b_off[1], s2 = b_off[2], s3 = b_off[3];
        #pragma unroll
        for (int q = 0; q < 4; q++) {
            s0 += part[(q * 64 + t) * 4 + 0];
            s1 += part[(q * 64 + t) * 4 + 1];
            s2 += part[(q * 64 + t) * 4 + 2];
            s3 += part[(q * 64 + t) * 4 + 3];
        }
        der[t * 4 + 0] = s0;                       // shift y
        der[t * 4 + 1] = s1;                       // shift x
        der[t * 4 + 2] = fmaxf(s2, 0.f) + 1.f;     // scale1 (corners)
        der[t * 4 + 3] = fmaxf(s3, 0.f) + 1.f;     // scale2 (edges)
    }
    __syncthreads();

    #pragma unroll
    for (int s = 0; s < 3; s++) {
        int q = t + s * 256;
        if (q < 576) {
            int k = q >> 6;
            int pp = q & 63;
            float sy = der[pp * 4 + 0], sx = der[pp * 4 + 1];
            float sc1 = der[pp * 4 + 2], sc2 = der[pp * 4 + 3];
            int ky = k / 3, kx = k - ky * 3;
            float by = (float)(ky - 1), bx = (float)(kx - 1);
            bool corner = (ky != 1) && (kx != 1);
            bool edge = (ky != 1) ^ (kx != 1);
            float sk = corner ? sc1 : (edge ? sc2 : 0.0f);
            // py = h + by + by*(sk-1) + sy = h + by*sk + sy
            float py = (float)h + by * sk + sy;
            float px = (float)pp + bx * sk + sx;
            float y0f = floorf(py), x0f = floorf(px);
            float wy = py - y0f, wx = px - x0f;
            int y0 = (int)y0f, x0 = (int)x0f;
            int y1 = y0 + 1, x1 = x0 + 1;
            float vy0 = (y0 >= 0 && y0 < Hd) ? 1.f : 0.f;
            float vy1 = (y1 >= 0 && y1 < Hd) ? 1.f : 0.f;
            float vx0 = (x0 >= 0 && x0 < Wd) ? 1.f : 0.f;
            float vx1 = (x1 >= 0 && x1 < Wd) ? 1.f : 0.f;
            int cy0 = min(max(y0, 0), Hd - 1), cy1 = min(max(y1, 0), Hd - 1);
            int cx0 = min(max(x0, 0), Wd - 1), cx1 = min(max(x1, 0), Wd - 1);
            int4 ii;
            ii.x = cy0 * Wd + cx0;
            ii.y = cy0 * Wd + cx1;
            ii.z = cy1 * Wd + cx0;
            ii.w = cy1 * Wd + cx1;
            float4 ww;
            ww.x = (1.f - wy) * (1.f - wx) * vy0 * vx0;
            ww.y = (1.f - wy) * wx * vy0 * vx1;
            ww.z = wy * (1.f - wx) * vy1 * vx0;
            ww.w = wy * wx * vy1 * vx1;
            int addr = (b * 9 + k) * HWp + h * Wd + pp;
            midx[addr] = ii;
            mw[addr] = ww;
        }
    }
}

// ---------------------------------------------------------------------------
// K3: fused gather + GEMM. block = (b, h-row): M=128 (all o), N=64 (one row),
// K=1152 in chunks of 36 (4 c x 9 k). 256 thr, 8x4 register tile each.
// ---------------------------------------------------------------------------
__global__ __launch_bounds__(256, 2) void deform_gemm_kernel(
    const float* __restrict__ x, const float* __restrict__ w_t,
    const float* __restrict__ bias, const int4* __restrict__ midx,
    const float4* __restrict__ mw, float* __restrict__ out)
{
    __shared__ float A_lds[36 * 128];   // [kk][o]
    __shared__ float S_lds[36 * 64];    // [kk][p]

    int t = threadIdx.x;
    int b = blockIdx.x >> 6;
    int h = blockIdx.x & 63;
    int p0 = h << 6;
    const float* xb = x + (size_t)b * CIN_ * HWp;

    // gather metadata: thread owns (k,p) pairs q = t, t+256, (t+512 if t<64)
    int k0 = t >> 6, pp0 = t & 63;
    int k1 = (t + 256) >> 6;             // pp1 == pp0
    int4 mi0, mi1, mi2 = make_int4(0, 0, 0, 0);
    float4 mw0, mw1, mw2 = make_float4(0.f, 0.f, 0.f, 0.f);
    {
        int a0 = (b * 9 + k0) * HWp + p0 + pp0;
        mi0 = midx[a0]; mw0 = mw[a0];
        int a1 = (b * 9 + k1) * HWp + p0 + pp0;
        mi1 = midx[a1]; mw1 = mw[a1];
        if (t < 64) {
            int a2 = (b * 9 + 8) * HWp + p0 + t;
            mi2 = midx[a2]; mw2 = mw[a2];
        }
    }

    float acc[8][4];
    #pragma unroll
    for (int i = 0; i < 8; i++)
        #pragma unroll
        for (int j = 0; j < 4; j++) acc[i][j] = 0.f;

    int og = t >> 4, pq = t & 15;

    for (int c0 = 0; c0 < CIN_; c0 += 4) {
        // stage A tile: 36 rows x 128 o, coalesced, conflict-free
        const float* wsrc = w_t + c0 * 9 * 128;
        #pragma unroll
        for (int i = 0; i < 18; i++) {
            int lin = t + i * 256;
            A_lds[lin] = wsrc[lin];
        }
        // produce S tile via gathers (metadata in registers)
        #pragma unroll
        for (int ccc = 0; ccc < 4; ccc++) {
            const float* xp = xb + (size_t)(c0 + ccc) * HWp;
            float v0 = mw0.x * xp[mi0.x] + mw0.y * xp[mi0.y]
                     + mw0.z * xp[mi0.z] + mw0.w * xp[mi0.w];
            S_lds[(ccc * 9 + k0) * 64 + pp0] = v0;
            float v1 = mw1.x * xp[mi1.x] + mw1.y * xp[mi1.y]
                     + mw1.z * xp[mi1.z] + mw1.w * xp[mi1.w];
            S_lds[(ccc * 9 + k1) * 64 + pp0] = v1;
            if (t < 64) {
                float v2 = mw2.x * xp[mi2.x] + mw2.y * xp[mi2.y]
                         + mw2.z * xp[mi2.z] + mw2.w * xp[mi2.w];
                S_lds[(ccc * 9 + 8) * 64 + t] = v2;
            }
        }
        __syncthreads();

        #pragma unroll 6
        for (int kk = 0; kk < 36; kk++) {
            float4 a0 = *(const float4*)&A_lds[kk * 128 + og * 8];
            float4 a1 = *(const float4*)&A_lds[kk * 128 + og * 8 + 4];
            float4 b4 = *(const float4*)&S_lds[kk * 64 + pq * 4];
            float av[8] = {a0.x, a0.y, a0.z, a0.w, a1.x, a1.y, a1.z, a1.w};
            float bv[4] = {b4.x, b4.y, b4.z, b4.w};
            #pragma unroll
            for (int i = 0; i < 8; i++)
                #pragma unroll
                for (int j = 0; j < 4; j++)
                    acc[i][j] += av[i] * bv[j];
        }
        __syncthreads();
    }

    #pragma unroll
    for (int i = 0; i < 8; i++) {
        int o = og * 8 + i;
        float bvs = bias[o];
        float4 r;
        r.x = acc[i][0] + bvs;
        r.y = acc[i][1] + bvs;
        r.z = acc[i][2] + bvs;
        r.w = acc[i][3] + bvs;
        *(float4*)&out[(size_t)(b * COUT_ + o) * HWp + p0 + pq * 4] = r;
    }
}

extern "C" void kernel_launch(void* const* d_in, const int* in_sizes, int n_in,
                              void* d_out, int out_size, void* d_ws, size_t ws_size,
                              hipStream_t stream) {
    const float* x     = (const float*)d_in[0];
    const float* w_off = (const float*)d_in[1];
    const float* b_off = (const float*)d_in[2];
    const float* w     = (const float*)d_in[3];
    const float* bias  = (const float*)d_in[4];
    float* out = (float*)d_out;

    char* ws = (char*)d_ws;
    float* w_t  = (float*)ws;                          // 147456 floats
    int4*  midx = (int4*)(ws + 589824);                // 8*9*4096 int4
    float4* mwp = (float4*)(ws + 589824 + 4718592);    // 8*9*4096 float4

    repack_w_kernel<<<576, 256, 0, stream>>>(w, w_t);
    offsets_kernel<<<512, 256, 0, stream>>>(x, w_off, b_off, midx, mwp);
    deform_gemm_kernel<<<512, 256, 0, stream>>>(x, w_t, bias, midx, mwp, out);
}

// Round 2
// 227.998 us; speedup vs baseline: 1.3613x; 1.3613x over previous
//
#include <hip/hip_runtime.h>

#define HWp 4096
#define Wd 64
#define Hd 64
#define CIN_ 128
#define COUT_ 128

typedef __bf16 bf16x8 __attribute__((ext_vector_type(8)));
typedef float f32x4 __attribute__((ext_vector_type(4)));

__device__ inline ushort f2bf(float f) {
    unsigned u = __float_as_uint(f);
    u += 0x7fff + ((u >> 16) & 1);          // round-to-nearest-even
    return (ushort)(u >> 16);
}

// ---------------------------------------------------------------------------
// K1w: repack main w (o,c,ky,kx) fp32 -> bf16 w_t[((k*4+q)*128 + o)*32 + ci]
//      (tap k 0..8, c-chunk q 0..3, ci = c within chunk)
// ---------------------------------------------------------------------------
__global__ __launch_bounds__(256) void repack_w_kernel(
    const float* __restrict__ w, ushort* __restrict__ w_t)
{
    int i = blockIdx.x * 256 + threadIdx.x;   // 147456 total
    int ci = i & 31;
    int o  = (i >> 5) & 127;
    int q  = (i >> 12) & 3;
    int k  = i >> 14;
    float v = w[o * 1152 + (q * 32 + ci) * 9 + k];
    w_t[i] = f2bf(v);
}

// ---------------------------------------------------------------------------
// K1o: repack offset weights w_off[5][128][9] -> wr[c][tap][j] fp32 (j=0..3)
// ---------------------------------------------------------------------------
__global__ __launch_bounds__(256) void repack_woff_kernel(
    const float* __restrict__ w_off, float* __restrict__ wr)
{
    int i = blockIdx.x * 256 + threadIdx.x;   // 4608 total
    int j = i & 3;
    int r = i >> 2;                            // c*9 + tap
    int tap = r % 9;
    int c = r / 9;
    wr[c * 36 + tap * 4 + j] = w_off[j * 1152 + c * 9 + tap];
}

// ---------------------------------------------------------------------------
// K2: offset conv (4 used channels) + bilinear metadata per (b,k,p).
// Weights read via wave-uniform pointer -> s_load (scalar pipe), no LDS.
// ---------------------------------------------------------------------------
__global__ __launch_bounds__(256, 2) void offsets_kernel(
    const float* __restrict__ x, const float* __restrict__ wr,
    const float* __restrict__ b_off, int4* __restrict__ midx,
    float4* __restrict__ mw)
{
    __shared__ float part[256 * 4];
    __shared__ float der[64 * 4];    // per position: sy, sx, scale1, scale2

    int t = threadIdx.x;
    int b = blockIdx.x >> 6;
    int h = blockIdx.x & 63;

    int pi = t & 63;   // w coordinate
    int cc = __builtin_amdgcn_readfirstlane(t >> 6);   // wave-uniform c-chunk
    const float* xb = x + (size_t)(b * CIN_ + cc * 32) * HWp;
    const float* wcc = wr + cc * 32 * 36;
    float o0 = 0.f, o1 = 0.f, o2 = 0.f, o3 = 0.f;

    for (int c = 0; c < 32; c++) {
        const float* xp = xb + c * HWp;
        const float* wc = wcc + c * 36;
        #pragma unroll
        for (int dy = -1; dy <= 1; dy++) {
            int hy = h + dy;
            if (hy < 0 || hy >= Hd) continue;      // wave-uniform
            const float* row = xp + hy * Wd;
            #pragma unroll
            for (int dx = -1; dx <= 1; dx++) {
                int wxc = pi + dx;
                float v = (wxc >= 0 && wxc < Wd) ? row[wxc] : 0.0f;
                int tap = (dy + 1) * 3 + (dx + 1);
                float4 wj = *(const float4*)&wc[tap * 4];   // s_load_dwordx4
                o0 += v * wj.x; o1 += v * wj.y; o2 += v * wj.z; o3 += v * wj.w;
            }
        }
    }
    part[t * 4 + 0] = o0;
    part[t * 4 + 1] = o1;
    part[t * 4 + 2] = o2;
    part[t * 4 + 3] = o3;
    __syncthreads();

    if (t < 64) {
        float s0 = b_off[0], s1 = b_off[1], s2 = b_off[2], s3 = b_off[3];
        #pragma unroll
        for (int q = 0; q < 4; q++) {
            s0 += part[(q * 64 + t) * 4 + 0];
            s1 += part[(q * 64 + t) * 4 + 1];
            s2 += part[(q * 64 + t) * 4 + 2];
            s3 += part[(q * 64 + t) * 4 + 3];
        }
        der[t * 4 + 0] = s0;
        der[t * 4 + 1] = s1;
        der[t * 4 + 2] = fmaxf(s2, 0.f) + 1.f;
        der[t * 4 + 3] = fmaxf(s3, 0.f) + 1.f;
    }
    __syncthreads();

    #pragma unroll
    for (int s = 0; s < 3; s++) {
        int q = t + s * 256;
        if (q < 576) {
            int k = q >> 6;
            int pp = q & 63;
            float sy = der[pp * 4 + 0], sx = der[pp * 4 + 1];
            float sc1 = der[pp * 4 + 2], sc2 = der[pp * 4 + 3];
            int ky = k / 3, kx = k - ky * 3;
            float by = (float)(ky - 1), bx = (float)(kx - 1);
            bool corner = (ky != 1) && (kx != 1);
            bool edge = (ky != 1) ^ (kx != 1);
            float sk = corner ? sc1 : (edge ? sc2 : 0.0f);
            float py = (float)h + by * sk + sy;
            float px = (float)pp + bx * sk + sx;
            float y0f = floorf(py), x0f = floorf(px);
            float wy = py - y0f, wx = px - x0f;
            int y0 = (int)y0f, x0 = (int)x0f;
            int y1 = y0 + 1, x1 = x0 + 1;
            float vy0 = (y0 >= 0 && y0 < Hd) ? 1.f : 0.f;
            float vy1 = (y1 >= 0 && y1 < Hd) ? 1.f : 0.f;
            float vx0 = (x0 >= 0 && x0 < Wd) ? 1.f : 0.f;
            float vx1 = (x1 >= 0 && x1 < Wd) ? 1.f : 0.f;
            int cy0 = min(max(y0, 0), Hd - 1), cy1 = min(max(y1, 0), Hd - 1);
            int cx0 = min(max(x0, 0), Wd - 1), cx1 = min(max(x1, 0), Wd - 1);
            int4 ii;
            ii.x = cy0 * Wd + cx0;
            ii.y = cy0 * Wd + cx1;
            ii.z = cy1 * Wd + cx0;
            ii.w = cy1 * Wd + cx1;
            float4 ww;
            ww.x = (1.f - wy) * (1.f - wx) * vy0 * vx0;
            ww.y = (1.f - wy) * wx * vy0 * vx1;
            ww.z = wy * (1.f - wx) * vy1 * vx0;
            ww.w = wy * wx * vy1 * vx1;
            int addr = (b * 9 + k) * HWp + h * Wd + pp;
            midx[addr] = ii;
            mw[addr] = ww;
        }
    }
}

// ---------------------------------------------------------------------------
// K3: fused gather + bf16 MFMA GEMM.
// Block = (b, 2 h-rows): M=128 (all o), N=128 positions, K=1152 in 36 chunks
// of 32 c (tap outer). 256 thr = 4 waves 2x2, wave tile 64x64, 16x16x32 MFMA.
// Double-buffered LDS, rows padded to 40 bf16 (80 B) -> conflict-light b128.
// ---------------------------------------------------------------------------
__global__ __launch_bounds__(256, 1) void deform_gemm_mfma(
    const float* __restrict__ x, const ushort* __restrict__ w_t,
    const float* __restrict__ bias, const int4* __restrict__ midx,
    const float4* __restrict__ mw, float* __restrict__ out)
{
    __shared__ ushort A_lds[2][128 * 40];
    __shared__ ushort S_lds[2][128 * 40];

    int t = threadIdx.x;
    int b = blockIdx.x >> 5;       // 0..7
    int rp = blockIdx.x & 31;      // row-pair 0..31
    int p0 = rp * 128;
    const float* xb = x + (size_t)b * CIN_ * HWp;

    // producer identity: p = position in tile, chalf = which 16-c half
    int p = t & 127;
    int chalf = t >> 7;            // wave-uniform (waves 0,1 -> 0; 2,3 -> 1)

    // MFMA identity
    int wv = t >> 6, lane = t & 63;
    int wm = wv & 1, wn = wv >> 1;
    int lm = lane & 15, lq = lane >> 4;

    f32x4 acc[4][4] = {};

    int4 mi;
    float4 mv;
    {
        int a0 = (b * 9 + 0) * HWp + p0 + p;
        mi = midx[a0];
        mv = mw[a0];
    }

    // ---- prologue: produce chunk 0 (tap 0, q 0) into buffer 0 ----
    {
        float g0[16], g1[16], g2[16], g3[16];
        const float* xc = xb + (size_t)(chalf * 16) * HWp;
        #pragma unroll
        for (int j = 0; j < 16; j++) {
            const float* xp = xc + (size_t)j * HWp;
            g0[j] = xp[mi.x]; g1[j] = xp[mi.y];
            g2[j] = xp[mi.z]; g3[j] = xp[mi.w];
        }
        int4 wa0 = *(const int4*)(w_t + t * 16);
        int4 wa1 = *(const int4*)(w_t + t * 16 + 8);
        ushort sv[16];
        #pragma unroll
        for (int j = 0; j < 16; j++) {
            float v = mv.x * g0[j] + mv.y * g1[j] + mv.z * g2[j] + mv.w * g3[j];
            sv[j] = f2bf(v);
        }
        *(int4*)&S_lds[0][p * 40 + chalf * 16]     = *(int4*)&sv[0];
        *(int4*)&S_lds[0][p * 40 + chalf * 16 + 8] = *(int4*)&sv[8];
        *(int4*)&A_lds[0][(t >> 1) * 40 + (t & 1) * 16]     = wa0;
        *(int4*)&A_lds[0][(t >> 1) * 40 + (t & 1) * 16 + 8] = wa1;
    }
    __syncthreads();

    // ---- main pipelined K loop: 36 chunks ----
    for (int s = 0; s < 36; s++) {
        int cur = s & 1, nb = cur ^ 1;
        int nxt = s + 1;
        bool produce = (nxt < 36);
        float g0[16], g1[16], g2[16], g3[16];
        int4 wa0 = {}, wa1 = {};
        if (produce) {
            int k = nxt >> 2, q = nxt & 3;
            if ((nxt & 3) == 0) {          // new tap: reload metadata
                int a0 = (b * 9 + k) * HWp + p0 + p;
                mi = midx[a0];
                mv = mw[a0];
            }
            const float* xc = xb + (size_t)(q * 32 + chalf * 16) * HWp;
            #pragma unroll
            for (int j = 0; j < 16; j++) {
                const float* xp = xc + (size_t)j * HWp;
                g0[j] = xp[mi.x]; g1[j] = xp[mi.y];
                g2[j] = xp[mi.z]; g3[j] = xp[mi.w];
            }
            wa0 = *(const int4*)(w_t + nxt * 4096 + t * 16);
            wa1 = *(const int4*)(w_t + nxt * 4096 + t * 16 + 8);
        }

        // MFMA on current buffers (hides the gather latency above)
        bf16x8 af[4], bfr[4];
        #pragma unroll
        for (int i = 0; i < 4; i++)
            af[i] = *(const bf16x8*)&A_lds[cur][(wm * 64 + i * 16 + lm) * 40 + lq * 8];
        #pragma unroll
        for (int j = 0; j < 4; j++)
            bfr[j] = *(const bf16x8*)&S_lds[cur][(wn * 64 + j * 16 + lm) * 40 + lq * 8];
        #pragma unroll
        for (int i = 0; i < 4; i++)
            #pragma unroll
            for (int j = 0; j < 4; j++)
                acc[i][j] = __builtin_amdgcn_mfma_f32_16x16x32_bf16(
                    af[i], bfr[j], acc[i][j], 0, 0, 0);

        if (produce) {
            ushort sv[16];
            #pragma unroll
            for (int j = 0; j < 16; j++) {
                float v = mv.x * g0[j] + mv.y * g1[j] + mv.z * g2[j] + mv.w * g3[j];
                sv[j] = f2bf(v);
            }
            *(int4*)&S_lds[nb][p * 40 + chalf * 16]     = *(int4*)&sv[0];
            *(int4*)&S_lds[nb][p * 40 + chalf * 16 + 8] = *(int4*)&sv[8];
            *(int4*)&A_lds[nb][(t >> 1) * 40 + (t & 1) * 16]     = wa0;
            *(int4*)&A_lds[nb][(t >> 1) * 40 + (t & 1) * 16 + 8] = wa1;
        }
        __syncthreads();
    }

    // ---- epilogue: C layout col(p)=lane&15, row(o)=(lane>>4)*4+reg ----
    #pragma unroll
    for (int i = 0; i < 4; i++) {
        #pragma unroll
        for (int r = 0; r < 4; r++) {
            int o = wm * 64 + i * 16 + lq * 4 + r;
            float bv = bias[o];
            float* orow = out + (size_t)(b * COUT_ + o) * HWp + p0 + wn * 64 + lm;
            #pragma unroll
            for (int j = 0; j < 4; j++)
                orow[j * 16] = acc[i][j][r] + bv;
        }
    }
}

extern "C" void kernel_launch(void* const* d_in, const int* in_sizes, int n_in,
                              void* d_out, int out_size, void* d_ws, size_t ws_size,
                              hipStream_t stream) {
    const float* x     = (const float*)d_in[0];
    const float* w_off = (const float*)d_in[1];
    const float* b_off = (const float*)d_in[2];
    const float* w     = (const float*)d_in[3];
    const float* bias  = (const float*)d_in[4];
    float* out = (float*)d_out;

    char* ws = (char*)d_ws;
    ushort* w_t  = (ushort*)ws;                             // 147456 bf16 = 294912 B
    int4*   midx = (int4*)(ws + 294912);                    // 8*9*4096 * 16 B
    float4* mwp  = (float4*)(ws + 294912 + 4718592);        // 8*9*4096 * 16 B
    float*  wr   = (float*)(ws + 294912 + 2 * 4718592);     // 4608 floats

    repack_w_kernel<<<576, 256, 0, stream>>>(w, w_t);
    repack_woff_kernel<<<18, 256, 0, stream>>>(w_off, wr);
    offsets_kernel<<<512, 256, 0, stream>>>(x, wr, b_off, midx, mwp);
    deform_gemm_mfma<<<256, 256, 0, stream>>>(x, w_t, bias, midx, mwp, out);
}

// Round 3
// 127.121 us; speedup vs baseline: 2.4415x; 1.7936x over previous
//
#include <hip/hip_runtime.h>

#define Wd 64
#define Hd 64
#define HWp 4096
#define CIN_ 128
#define COUT_ 128

typedef __bf16 bf16x8 __attribute__((ext_vector_type(8)));
typedef float f32x4 __attribute__((ext_vector_type(4)));

__device__ inline ushort f2bf(float f) {
    unsigned u = __float_as_uint(f);
    u += 0x7fff + ((u >> 16) & 1);          // round-to-nearest-even
    return (ushort)(u >> 16);
}
__device__ inline float bflo(unsigned u) { return __uint_as_float(u << 16); }
__device__ inline float bfhi(unsigned u) { return __uint_as_float(u & 0xffff0000u); }
__device__ inline unsigned bfround(float f) {
    unsigned u = __float_as_uint(f);
    return u + 0x7fff + ((u >> 16) & 1);
}
__device__ inline unsigned pack2(float lo, float hi) {
    // dest = { hi.b3, hi.b2, lo.b3, lo.b2 }
    return __builtin_amdgcn_perm(bfround(hi), bfround(lo), 0x07060302);
}

// ---------------------------------------------------------------------------
// K_prep (one launch, 850 blocks):
//   blk 0..255   : transpose x NCHW f32 -> xt[b][yx][c] bf16 (128yx x 128c tile)
//   blk 256..831 : repack main w -> bf16 w_t[(s*128 + o)*32 + ci], s=k*4+q
//   blk 832..849 : repack offset weights -> wr[c][tap][j] f32
// ---------------------------------------------------------------------------
__global__ __launch_bounds__(256) void prep_kernel(
    const float* __restrict__ x, const float* __restrict__ w,
    const float* __restrict__ w_off, ushort* __restrict__ xt,
    ushort* __restrict__ w_t, float* __restrict__ wr)
{
    __shared__ ushort tile[128 * 136];
    int blk = blockIdx.x;
    int t = threadIdx.x;

    if (blk < 256) {
        int b = blk >> 5, yx0 = (blk & 31) << 7;
        const float* xb = x + (size_t)b * CIN_ * HWp + yx0;
        int lanelo = t & 31, grp = t >> 5;          // grp 0..7
        #pragma unroll
        for (int i = 0; i < 4; i++) {
            int cbase = i * 32 + grp * 4;
            float4 v0 = *(const float4*)(xb + (size_t)(cbase + 0) * HWp + lanelo * 4);
            float4 v1 = *(const float4*)(xb + (size_t)(cbase + 1) * HWp + lanelo * 4);
            float4 v2 = *(const float4*)(xb + (size_t)(cbase + 2) * HWp + lanelo * 4);
            float4 v3 = *(const float4*)(xb + (size_t)(cbase + 3) * HWp + lanelo * 4);
            ushort4 u;
            u.x = f2bf(v0.x); u.y = f2bf(v1.x); u.z = f2bf(v2.x); u.w = f2bf(v3.x);
            *(ushort4*)&tile[(lanelo * 4 + 0) * 136 + cbase] = u;
            u.x = f2bf(v0.y); u.y = f2bf(v1.y); u.z = f2bf(v2.y); u.w = f2bf(v3.y);
            *(ushort4*)&tile[(lanelo * 4 + 1) * 136 + cbase] = u;
            u.x = f2bf(v0.z); u.y = f2bf(v1.z); u.z = f2bf(v2.z); u.w = f2bf(v3.z);
            *(ushort4*)&tile[(lanelo * 4 + 2) * 136 + cbase] = u;
            u.x = f2bf(v0.w); u.y = f2bf(v1.w); u.z = f2bf(v2.w); u.w = f2bf(v3.w);
            *(ushort4*)&tile[(lanelo * 4 + 3) * 136 + cbase] = u;
        }
        __syncthreads();
        ushort* dst = xt + ((size_t)b * HWp + yx0) * CIN_;
        int c8 = (t & 15) * 8, yxg = t >> 4;
        #pragma unroll
        for (int i = 0; i < 8; i++) {
            int yxl = i * 16 + yxg;
            int4 v = *(int4*)&tile[yxl * 136 + c8];
            *(int4*)(dst + (size_t)yxl * CIN_ + c8) = v;
        }
    } else if (blk < 832) {
        int i = (blk - 256) * 256 + t;              // 147456 total
        int ci = i & 31, o = (i >> 5) & 127, s = i >> 12;
        int k = s >> 2, q = s & 3, c = q * 32 + ci;
        w_t[i] = f2bf(w[o * 1152 + c * 9 + k]);
    } else {
        int i = (blk - 832) * 256 + t;              // 4608 total
        if (i < 4608) {
            int j = i & 3, r = i >> 2;
            int tap = r % 9, c = r / 9;
            wr[c * 36 + tap * 4 + j] = w_off[j * 1152 + c * 9 + tap];
        }
    }
}

// ---------------------------------------------------------------------------
// K2: offset conv (4 used channels) + bilinear metadata per (b,k,p).
// Weights in LDS, read as wave-uniform broadcast b128 (free).
// ---------------------------------------------------------------------------
__global__ __launch_bounds__(256, 2) void offsets_kernel(
    const float* __restrict__ x, const float* __restrict__ wr,
    const float* __restrict__ b_off, int4* __restrict__ midx,
    float4* __restrict__ mw)
{
    __shared__ float wl[4608];
    __shared__ float part[256 * 4];
    __shared__ float der[64 * 4];

    int t = threadIdx.x;
    int b = blockIdx.x >> 6;
    int h = blockIdx.x & 63;

    for (int i = t; i < 4608; i += 256) wl[i] = wr[i];
    __syncthreads();

    int pi = t & 63, cc = t >> 6;
    const float* xb = x + (size_t)(b * CIN_ + cc * 32) * HWp;

    // precompute clamped neighbor offsets + masks (branchless loads)
    int idx9[9];
    float msk9[9];
    #pragma unroll
    for (int dy = 0; dy < 3; dy++) {
        int hy = h + dy - 1;
        int hyc = min(max(hy, 0), Hd - 1);
        bool vr = (hy >= 0) && (hy < Hd);
        #pragma unroll
        for (int dx = 0; dx < 3; dx++) {
            int wx = pi + dx - 1;
            int wxc = min(max(wx, 0), Wd - 1);
            bool v = vr && (wx >= 0) && (wx < Wd);
            idx9[dy * 3 + dx] = hyc * Wd + wxc;
            msk9[dy * 3 + dx] = v ? 1.0f : 0.0f;
        }
    }

    float o0 = 0.f, o1 = 0.f, o2 = 0.f, o3 = 0.f;
    #pragma unroll 2
    for (int c = 0; c < 32; c++) {
        const float* xp = xb + c * HWp;
        const float* wc = &wl[(cc * 32 + c) * 36];
        float xv[9];
        #pragma unroll
        for (int tp = 0; tp < 9; tp++) xv[tp] = xp[idx9[tp]] * msk9[tp];
        #pragma unroll
        for (int tp = 0; tp < 9; tp++) {
            float4 wj = *(const float4*)&wc[tp * 4];
            o0 += xv[tp] * wj.x; o1 += xv[tp] * wj.y;
            o2 += xv[tp] * wj.z; o3 += xv[tp] * wj.w;
        }
    }
    part[t * 4 + 0] = o0;
    part[t * 4 + 1] = o1;
    part[t * 4 + 2] = o2;
    part[t * 4 + 3] = o3;
    __syncthreads();

    if (t < 64) {
        float s0 = b_off[0], s1 = b_off[1], s2 = b_off[2], s3 = b_off[3];
        #pragma unroll
        for (int q = 0; q < 4; q++) {
            s0 += part[(q * 64 + t) * 4 + 0];
            s1 += part[(q * 64 + t) * 4 + 1];
            s2 += part[(q * 64 + t) * 4 + 2];
            s3 += part[(q * 64 + t) * 4 + 3];
        }
        der[t * 4 + 0] = s0;
        der[t * 4 + 1] = s1;
        der[t * 4 + 2] = fmaxf(s2, 0.f) + 1.f;
        der[t * 4 + 3] = fmaxf(s3, 0.f) + 1.f;
    }
    __syncthreads();

    #pragma unroll
    for (int s = 0; s < 3; s++) {
        int q = t + s * 256;
        if (q < 576) {
            int k = q >> 6;
            int pp = q & 63;
            float sy = der[pp * 4 + 0], sx = der[pp * 4 + 1];
            float sc1 = der[pp * 4 + 2], sc2 = der[pp * 4 + 3];
            int ky = k / 3, kx = k - ky * 3;
            float by = (float)(ky - 1), bx = (float)(kx - 1);
            bool corner = (ky != 1) && (kx != 1);
            bool edge = (ky != 1) ^ (kx != 1);
            float sk = corner ? sc1 : (edge ? sc2 : 0.0f);
            float py = (float)h + by * sk + sy;
            float px = (float)pp + bx * sk + sx;
            float y0f = floorf(py), x0f = floorf(px);
            float wy = py - y0f, wx = px - x0f;
            int y0 = (int)y0f, x0 = (int)x0f;
            int y1 = y0 + 1, x1 = x0 + 1;
            float vy0 = (y0 >= 0 && y0 < Hd) ? 1.f : 0.f;
            float vy1 = (y1 >= 0 && y1 < Hd) ? 1.f : 0.f;
            float vx0 = (x0 >= 0 && x0 < Wd) ? 1.f : 0.f;
            float vx1 = (x1 >= 0 && x1 < Wd) ? 1.f : 0.f;
            int cy0 = min(max(y0, 0), Hd - 1), cy1 = min(max(y1, 0), Hd - 1);
            int cx0 = min(max(x0, 0), Wd - 1), cx1 = min(max(x1, 0), Wd - 1);
            int4 ii;
            ii.x = cy0 * Wd + cx0;
            ii.y = cy0 * Wd + cx1;
            ii.z = cy1 * Wd + cx0;
            ii.w = cy1 * Wd + cx1;
            float4 ww;
            ww.x = (1.f - wy) * (1.f - wx) * vy0 * vx0;
            ww.y = (1.f - wy) * wx * vy0 * vx1;
            ww.z = wy * (1.f - wx) * vy1 * vx0;
            ww.w = wy * wx * vy1 * vx1;
            int addr = (b * 9 + k) * HWp + h * Wd + pp;
            midx[addr] = ii;
            mw[addr] = ww;
        }
    }
}

// ---------------------------------------------------------------------------
// K3: fused gather (NHWC-bf16, line-aligned) + bf16 MFMA GEMM.
// Block = (b, 2 h-rows): M=128, N=128, K=1152 in 36 chunks of 32 c.
// 512 thr = 8 waves (2 M x 4 N), wave tile 64x32, double-buffered LDS.
// ---------------------------------------------------------------------------
struct Gath { int4 g0, g1, g2, g3, wa; };

__global__ __launch_bounds__(512, 2) void deform_gemm_mfma(
    const ushort* __restrict__ xt, const ushort* __restrict__ w_t,
    const float* __restrict__ bias, const int4* __restrict__ midx,
    const float4* __restrict__ mw, float* __restrict__ out)
{
    __shared__ ushort A_lds[2][128 * 40];
    __shared__ ushort S_lds[2][128 * 40];

    int t = threadIdx.x;
    int b = blockIdx.x >> 5;
    int rp = blockIdx.x & 31;
    int p0 = rp << 7;
    const ushort* xtb = xt + (size_t)b * HWp * CIN_;

    int p = t >> 2;                 // 0..127 position in tile
    int c8 = (t & 3) << 3;          // channel offset within 32-chunk

    int wv = t >> 6, lane = t & 63;
    int wm = wv & 1, wn = wv >> 1;  // wn 0..3
    int lm = lane & 15, lq = lane >> 4;

    f32x4 acc[4][2] = {};

    int4 mi = midx[(b * 9 + 0) * HWp + p0 + p];
    float4 mv = mw[(b * 9 + 0) * HWp + p0 + p];

    auto issue = [&](int s) -> Gath {
        int q = s & 3;
        const ushort* base = xtb + q * 32 + c8;
        Gath r;
        r.g0 = *(const int4*)(base + mi.x * CIN_);
        r.g1 = *(const int4*)(base + mi.y * CIN_);
        r.g2 = *(const int4*)(base + mi.z * CIN_);
        r.g3 = *(const int4*)(base + mi.w * CIN_);
        r.wa = *(const int4*)(w_t + s * 4096 + t * 8);
        return r;
    };
    auto commit = [&](int nb, const Gath& G) {
        const unsigned* u0 = (const unsigned*)&G.g0;
        const unsigned* u1 = (const unsigned*)&G.g1;
        const unsigned* u2 = (const unsigned*)&G.g2;
        const unsigned* u3 = (const unsigned*)&G.g3;
        unsigned sd[4];
        #pragma unroll
        for (int d = 0; d < 4; d++) {
            float vlo = mv.x * bflo(u0[d]) + mv.y * bflo(u1[d])
                      + mv.z * bflo(u2[d]) + mv.w * bflo(u3[d]);
            float vhi = mv.x * bfhi(u0[d]) + mv.y * bfhi(u1[d])
                      + mv.z * bfhi(u2[d]) + mv.w * bfhi(u3[d]);
            sd[d] = pack2(vlo, vhi);
        }
        *(int4*)&S_lds[nb][p * 40 + c8] = *(const int4*)sd;
        *(int4*)&A_lds[nb][(t >> 2) * 40 + c8] = G.wa;
    };

    // prologue: chunk 0 -> buffer 0
    {
        Gath G = issue(0);
        commit(0, G);
    }
    __syncthreads();

    for (int s = 0; s < 36; s++) {
        int cur = s & 1;
        bool prod = (s + 1 < 36);
        Gath Gn;
        if (prod) {
            if (((s + 1) & 3) == 0) {
                int k = (s + 1) >> 2;
                mi = midx[(b * 9 + k) * HWp + p0 + p];
                mv = mw[(b * 9 + k) * HWp + p0 + p];
            }
            Gn = issue(s + 1);
        }

        bf16x8 af[4], bfr[2];
        #pragma unroll
        for (int i = 0; i < 4; i++)
            af[i] = *(const bf16x8*)&A_lds[cur][(wm * 64 + i * 16 + lm) * 40 + lq * 8];
        #pragma unroll
        for (int j = 0; j < 2; j++)
            bfr[j] = *(const bf16x8*)&S_lds[cur][(wn * 32 + j * 16 + lm) * 40 + lq * 8];
        #pragma unroll
        for (int i = 0; i < 4; i++)
            #pragma unroll
            for (int j = 0; j < 2; j++)
                acc[i][j] = __builtin_amdgcn_mfma_f32_16x16x32_bf16(
                    af[i], bfr[j], acc[i][j], 0, 0, 0);

        if (prod) commit(cur ^ 1, Gn);
        __syncthreads();
    }

    // epilogue: C layout col(p)=lane&15, row(o)=(lane>>4)*4+reg
    #pragma unroll
    for (int i = 0; i < 4; i++) {
        #pragma unroll
        for (int r = 0; r < 4; r++) {
            int o = wm * 64 + i * 16 + lq * 4 + r;
            float bv = bias[o];
            float* orow = out + (size_t)(b * COUT_ + o) * HWp + p0 + wn * 32 + lm;
            #pragma unroll
            for (int j = 0; j < 2; j++)
                orow[j * 16] = acc[i][j][r] + bv;
        }
    }
}

extern "C" void kernel_launch(void* const* d_in, const int* in_sizes, int n_in,
                              void* d_out, int out_size, void* d_ws, size_t ws_size,
                              hipStream_t stream) {
    const float* x     = (const float*)d_in[0];
    const float* w_off = (const float*)d_in[1];
    const float* b_off = (const float*)d_in[2];
    const float* w     = (const float*)d_in[3];
    const float* bias  = (const float*)d_in[4];
    float* out = (float*)d_out;

    char* ws = (char*)d_ws;
    ushort* xt   = (ushort*)ws;                          // 8 MiB
    ushort* w_t  = (ushort*)(ws + 8388608);              // 294912 B
    int4*   midx = (int4*)(ws + 8683520);                // 4.5 MiB
    float4* mwp  = (float4*)(ws + 13402112);             // 4.5 MiB
    float*  wr   = (float*)(ws + 18120704);              // 18432 B

    prep_kernel<<<850, 256, 0, stream>>>(x, w, w_off, xt, w_t, wr);
    offsets_kernel<<<512, 256, 0, stream>>>(x, wr, b_off, midx, mwp);
    deform_gemm_mfma<<<256, 512, 0, stream>>>(xt, w_t, bias, midx, mwp, out);
}